// Round 2
// baseline (1132.889 us; speedup 1.0000x reference)
//
#include <hip/hip_runtime.h>
#include <stdint.h>

// PlanStack: push = LN(hidden @ W_push^T + b_push); gate = sigmoid(hidden@w_pop^T+b_pop)>0.5
// Outputs (concat f32): new_stack (B,D,H) | new_pointer (B,1) | top (B,H) | popped (B,H)

#define Bsz 16384
#define Dd  8
#define Hh  1024
#define EPSf 1e-5f

typedef __attribute__((ext_vector_type(8))) short bf16x8;
typedef __attribute__((ext_vector_type(4))) float f32x4;

#define O_PTR  ((size_t)Bsz*Dd*Hh)           // 134217728
#define O_TOP  (O_PTR + Bsz)                 // 134234112
#define O_POP  (O_TOP + (size_t)Bsz*Hh)      // 151011328

static __device__ __forceinline__ unsigned short f2bf(float f){
  union { float f; unsigned u; } v; v.f = f;
  unsigned r = (v.u + 0x7fffu + ((v.u >> 16) & 1u)) >> 16;  // RNE
  return (unsigned short)r;
}

static __device__ __forceinline__ void gload16(const void* g, void* l){
  __builtin_amdgcn_global_load_lds((const __attribute__((address_space(1))) void*)g,
                                   (__attribute__((address_space(3))) void*)l, 16, 0, 0);
}

// ---------- kernel 0: W_push -> bf16, zero the push counter ----------
__global__ __launch_bounds__(256) void k_wconv(const float* __restrict__ W,
                                               unsigned short* __restrict__ Wb,
                                               int* __restrict__ counter){
  if (blockIdx.x == 0 && threadIdx.x == 0) *counter = 0;
  int i = (blockIdx.x * 256 + threadIdx.x) * 4;
  float4 v = *(const float4*)(W + i);
  ushort4 s; s.x = f2bf(v.x); s.y = f2bf(v.y); s.z = f2bf(v.z); s.w = f2bf(v.w);
  *(ushort4*)(Wb + i) = s;
}

// ---------- kernel 1: per-row gate + hidden->bf16 + new_pointer + push-row list ----------
__global__ __launch_bounds__(256) void k_prep(const float* __restrict__ hidden,
                                              const float* __restrict__ pointer,
                                              const float* __restrict__ w_pop,
                                              const float* __restrict__ b_pop,
                                              float* __restrict__ out,
                                              unsigned short* __restrict__ hbf,
                                              int* __restrict__ flags,
                                              int* __restrict__ list,
                                              int* __restrict__ counter){
  int row = blockIdx.x;
  int t   = threadIdx.x;
  float4 hv = *(const float4*)(hidden + (size_t)row * Hh + t * 4);
  float4 wv = *(const float4*)(w_pop + t * 4);
  ushort4 s; s.x = f2bf(hv.x); s.y = f2bf(hv.y); s.z = f2bf(hv.z); s.w = f2bf(hv.w);
  *(ushort4*)(hbf + (size_t)row * Hh + t * 4) = s;

  float d = hv.x*wv.x + hv.y*wv.y + hv.z*wv.z + hv.w*wv.w;
  #pragma unroll
  for (int o = 32; o > 0; o >>= 1) d += __shfl_down(d, o);
  __shared__ float part[4];
  if ((t & 63) == 0) part[t >> 6] = d;
  __syncthreads();
  if (t == 0){
    float logit = part[0] + part[1] + part[2] + part[3] + b_pop[0];
    int ptr = (int)pointer[row];
    bool is_pop  = logit > 0.0f;            // sigmoid(x) > 0.5  <=>  x > 0
    bool do_pop  = is_pop && (ptr > 0);
    bool do_push = (!is_pop) && (ptr < Dd);
    int np = do_pop ? (ptr - 1) : (do_push ? (ptr + 1) : ptr);
    out[O_PTR + row] = (float)np;
    flags[row] = ptr | (do_pop ? 256 : 0) | (do_push ? 512 : 0);
    if (do_push){ int p = atomicAdd(counter, 1); list[p] = row; }
  }
}

// ---------- kernel 2: stack copy + top (non-push) + popped ----------
__global__ __launch_bounds__(256) void k_copy(const float* __restrict__ stack,
                                              const int* __restrict__ flags,
                                              float* __restrict__ out){
  int row = blockIdx.x;
  int t   = threadIdx.x;
  int f = flags[row];
  int ptr = f & 255; bool do_pop = (f & 256) != 0; bool do_push = (f & 512) != 0;
  const float4* src = (const float4*)(stack + (size_t)row * Dd * Hh);
  float4*       dst = (float4*)(out   + (size_t)row * Dd * Hh);
  float4 prev = {0.f, 0.f, 0.f, 0.f};
  #pragma unroll
  for (int d = 0; d < Dd; ++d){
    float4 v = src[d * (Hh / 4) + t];
    if (d == ptr - 1) prev = v;
    if (!(do_push && d == ptr)) dst[d * (Hh / 4) + t] = v;  // push slot rewritten by k_ln
  }
  float4 z = {0.f, 0.f, 0.f, 0.f};
  *(float4*)(out + O_POP + (size_t)row * Hh + t * 4) = do_pop ? prev : z;
  if (!do_push)
    *(float4*)(out + O_TOP + (size_t)row * Hh + t * 4) = (ptr > 0) ? prev : z;
}

// ---------- kernel 3: compacted bf16 MFMA GEMM (raw push+bias -> top rows) ----------
__global__ __launch_bounds__(256) void k_gemm(const unsigned short* __restrict__ A,
                                              const unsigned short* __restrict__ Wb,
                                              const float* __restrict__ bias,
                                              const int* __restrict__ list,
                                              const int* __restrict__ cnt,
                                              float* __restrict__ out){
  __shared__ __align__(16) unsigned short Ab[128 * 64];
  __shared__ __align__(16) unsigned short Bb[128 * 64];
  int count = *cnt;
  int m0 = blockIdx.x * 128;
  if (m0 >= count) return;
  int n0 = blockIdx.y * 128;
  int t = threadIdx.x;
  int lane = t & 63, wv = t >> 6;
  int wm = wv >> 1, wn = wv & 1;           // 2x2 waves, each 64x64

  // staging addresses: thread t loads 16B chunk (t&7) of row it*32 + (t>>3)
  const unsigned short* aptr[4];
  const unsigned short* bptr[4];
  int chunk = t & 7;
  #pragma unroll
  for (int it = 0; it < 4; ++it){
    int r  = it * 32 + (t >> 3);
    int gr = m0 + r;
    int idx = list[(gr < count) ? gr : (count - 1)];
    aptr[it] = A  + (size_t)idx * Hh + chunk * 8;
    bptr[it] = Wb + (size_t)(n0 + r) * Hh + chunk * 8;
  }

  f32x4 acc[4][4] = {};
  for (int k0 = 0; k0 < Hh; k0 += 64){
    #pragma unroll
    for (int it = 0; it < 4; ++it) gload16(aptr[it] + k0, &Ab[it * 2048 + t * 8]);
    #pragma unroll
    for (int it = 0; it < 4; ++it) gload16(bptr[it] + k0, &Bb[it * 2048 + t * 8]);
    __syncthreads();   // compiler drains vmcnt before barrier
    int ro = lane & 15, ko = (lane >> 4) * 8;
    #pragma unroll
    for (int kk = 0; kk < 64; kk += 32){
      bf16x8 af[4], bfv[4];
      #pragma unroll
      for (int fm = 0; fm < 4; ++fm)
        af[fm] = *(const bf16x8*)&Ab[(wm * 64 + fm * 16 + ro) * 64 + kk + ko];
      #pragma unroll
      for (int fn = 0; fn < 4; ++fn)
        bfv[fn] = *(const bf16x8*)&Bb[(wn * 64 + fn * 16 + ro) * 64 + kk + ko];
      #pragma unroll
      for (int fm = 0; fm < 4; ++fm)
        #pragma unroll
        for (int fn = 0; fn < 4; ++fn)
          acc[fm][fn] = __builtin_amdgcn_mfma_f32_16x16x32_bf16(af[fm], bfv[fn], acc[fm][fn], 0, 0, 0);
    }
    __syncthreads();
  }

  // epilogue: C/D map col=lane&15, row=(lane>>4)*4+q  -> raw push into top region
  #pragma unroll
  for (int fm = 0; fm < 4; ++fm){
    #pragma unroll
    for (int q = 0; q < 4; ++q){
      int rc = m0 + wm * 64 + fm * 16 + (lane >> 4) * 4 + q;
      if (rc < count){
        int orow = list[rc];
        int col0 = n0 + wn * 64 + (lane & 15);
        float* o = out + O_TOP + (size_t)orow * Hh + col0;
        #pragma unroll
        for (int fn = 0; fn < 4; ++fn)
          o[fn * 16] = acc[fm][fn][q] + bias[col0 + fn * 16];
      }
    }
  }
}

// ---------- kernel 4: LayerNorm push rows in place + scatter into stack slot ----------
__global__ __launch_bounds__(256) void k_ln(const int* __restrict__ cnt,
                                            const int* __restrict__ list,
                                            const int* __restrict__ flags,
                                            const float* __restrict__ g,
                                            const float* __restrict__ b,
                                            float* __restrict__ out){
  int ci = blockIdx.x;
  if (ci >= *cnt) return;
  int row = list[ci];
  int t = threadIdx.x;
  float* top = out + O_TOP + (size_t)row * Hh;
  float4 v = *(float4*)(top + t * 4);
  float s1 = v.x + v.y + v.z + v.w;
  float s2 = v.x*v.x + v.y*v.y + v.z*v.z + v.w*v.w;
  #pragma unroll
  for (int o = 32; o > 0; o >>= 1){ s1 += __shfl_down(s1, o); s2 += __shfl_down(s2, o); }
  __shared__ float p1[4], p2[4];
  if ((t & 63) == 0){ p1[t >> 6] = s1; p2[t >> 6] = s2; }
  __syncthreads();
  float S1 = p1[0] + p1[1] + p1[2] + p1[3];
  float S2 = p2[0] + p2[1] + p2[2] + p2[3];
  float mu = S1 * (1.0f / Hh);
  float var = S2 * (1.0f / Hh) - mu * mu;
  float rstd = rsqrtf(var + EPSf);
  float4 gg = *(const float4*)(g + t * 4);
  float4 bb = *(const float4*)(b + t * 4);
  float4 r;
  r.x = (v.x - mu) * rstd * gg.x + bb.x;
  r.y = (v.y - mu) * rstd * gg.y + bb.y;
  r.z = (v.z - mu) * rstd * gg.z + bb.z;
  r.w = (v.w - mu) * rstd * gg.w + bb.w;
  *(float4*)(top + t * 4) = r;
  int ptr = flags[row] & 255;                      // slot to write (do_push => ptr < 8)
  *(float4*)(out + (size_t)row * Dd * Hh + ptr * Hh + t * 4) = r;
}

extern "C" void kernel_launch(void* const* d_in, const int* in_sizes, int n_in,
                              void* d_out, int out_size, void* d_ws, size_t ws_size,
                              hipStream_t stream) {
  const float* hidden  = (const float*)d_in[0];
  const float* stack   = (const float*)d_in[1];
  const float* pointer = (const float*)d_in[2];
  const float* W_push  = (const float*)d_in[3];
  const float* b_push  = (const float*)d_in[4];
  const float* ln_g    = (const float*)d_in[5];
  const float* ln_b    = (const float*)d_in[6];
  const float* w_pop   = (const float*)d_in[7];
  const float* b_pop   = (const float*)d_in[8];
  float* out = (float*)d_out;

  char* ws = (char*)d_ws;                                   // ~35.9 MB used
  unsigned short* hbf = (unsigned short*)ws;                // B*H bf16 = 32 MB
  unsigned short* wbf = (unsigned short*)(ws + (size_t)Bsz * Hh * 2);   // 2 MB
  int* flags   = (int*)(ws + (size_t)Bsz * Hh * 2 + (size_t)Hh * Hh * 2);
  int* list    = flags + Bsz;
  int* counter = list + Bsz;

  k_wconv<<<(Hh * Hh) / 1024, 256, 0, stream>>>(W_push, wbf, counter);
  k_prep <<<Bsz, 256, 0, stream>>>(hidden, pointer, w_pop, b_pop, out, hbf, flags, list, counter);
  k_copy <<<Bsz, 256, 0, stream>>>(stack, flags, out);
  dim3 gg(Bsz / 128, Hh / 128);
  k_gemm <<<gg, 256, 0, stream>>>(hbf, wbf, b_push, list, counter, out);
  k_ln   <<<Bsz, 256, 0, stream>>>(counter, list, flags, ln_g, ln_b, out);
}